// Round 1
// baseline (209.792 us; speedup 1.0000x reference)
//
#include <hip/hip_runtime.h>
#include <math.h>

#define E 4
#define TPB 256
#define RPB 8
#define NWAVES (TPB / 64)
#define SINKHORN_ITERS 20
#define SINKHORN_EPS 1e-6f

// ---------------------------------------------------------------------------
// Kernel 0: tiny prep. One block.
//  - sinkhorn(H_res_logits) -> H_res (4x4 doubly stochastic), thread 0 scalar.
//  - softmax rows of H_pre_logits -> ws_pre (E x D)
//  - ws_post2[e'][d] = sum_e H_res[e'][e] * softmax(H_post_logits)[e][d]
// ---------------------------------------------------------------------------
__global__ __launch_bounds__(TPB) void prep_kernel(
    const float* __restrict__ Hres_l,
    const float* __restrict__ Hpre_l,
    const float* __restrict__ Hpost_l,
    float* __restrict__ ws_pre,
    float* __restrict__ ws_post2,
    int D)
{
    __shared__ float sHres[E * E];
    __shared__ float red[TPB];
    __shared__ float mx_pre[E], sm_pre[E], mx_post[E], sm_post[E];
    const int t = threadIdx.x;

    if (t == 0) {
        float A[E * E];
        float m = -1e30f;
        for (int i = 0; i < E * E; ++i) { A[i] = Hres_l[i]; m = fmaxf(m, A[i]); }
        for (int i = 0; i < E * E; ++i) A[i] = expf(A[i] - m);
        for (int it = 0; it < SINKHORN_ITERS; ++it) {
            for (int r = 0; r < E; ++r) {
                float s = SINKHORN_EPS;
                for (int c = 0; c < E; ++c) s += A[r * E + c];
                for (int c = 0; c < E; ++c) A[r * E + c] /= s;
            }
            for (int c = 0; c < E; ++c) {
                float s = SINKHORN_EPS;
                for (int r = 0; r < E; ++r) s += A[r * E + c];
                for (int r = 0; r < E; ++r) A[r * E + c] /= s;
            }
        }
        for (int i = 0; i < E * E; ++i) sHres[i] = A[i];
    }
    __syncthreads();

    // row softmax stats (max, sumexp) for H_pre and H_post
    for (int mat = 0; mat < 2; ++mat) {
        const float* base = (mat == 0) ? Hpre_l : Hpost_l;
        float* mx = (mat == 0) ? mx_pre : mx_post;
        float* sm = (mat == 0) ? sm_pre : sm_post;
        for (int e = 0; e < E; ++e) {
            const float* rowp = base + (size_t)e * D;
            float m = -INFINITY;
            for (int i = t; i < D; i += TPB) m = fmaxf(m, rowp[i]);
            red[t] = m; __syncthreads();
            for (int s = TPB / 2; s > 0; s >>= 1) {
                if (t < s) red[t] = fmaxf(red[t], red[t + s]);
                __syncthreads();
            }
            float rm = red[0]; __syncthreads();
            float sum = 0.f;
            for (int i = t; i < D; i += TPB) sum += expf(rowp[i] - rm);
            red[t] = sum; __syncthreads();
            for (int s = TPB / 2; s > 0; s >>= 1) {
                if (t < s) red[t] += red[t + s];
                __syncthreads();
            }
            if (t == 0) { mx[e] = rm; sm[e] = red[0]; }
            __syncthreads();
        }
    }

    // write ws_pre = softmax(H_pre); ws_post2 = H_res-folded softmax(H_post)
    for (int i = t; i < D; i += TPB) {
        float post[E];
#pragma unroll
        for (int e = 0; e < E; ++e) {
            ws_pre[(size_t)e * D + i] = expf(Hpre_l[(size_t)e * D + i] - mx_pre[e]) / sm_pre[e];
            post[e] = expf(Hpost_l[(size_t)e * D + i] - mx_post[e]) / sm_post[e];
        }
#pragma unroll
        for (int ep = 0; ep < E; ++ep) {
            float acc = 0.f;
#pragma unroll
            for (int e = 0; e < E; ++e) acc += sHres[ep * E + e] * post[e];
            ws_post2[(size_t)ep * D + i] = acc;
        }
    }
}

// ---------------------------------------------------------------------------
// Kernel 1: main. One block = 256 threads handles RPB=8 consecutive rows.
//  Phase 1: x_pre[r][e] = dot(x[row], softmax_pre[e])  (block reduction)
//  Phase 2: out[row][d] = sum_e x_pre[r][e] * ws_post2[e][d]
// H fragments are hoisted to registers per 1024-float chunk and reused for
// all 8 rows -> H L2 traffic amortized 8x.
// ---------------------------------------------------------------------------
__global__ __launch_bounds__(TPB) void mhc_main(
    const float4* __restrict__ x4,
    const float4* __restrict__ pre4,    // E * D4
    const float4* __restrict__ post4,   // E * D4
    float4* __restrict__ out4,
    int D4, int chunks)
{
    __shared__ float wred[NWAVES][E][RPB];
    const int t = threadIdx.x;
    const int wave = t >> 6;
    const long row0 = (long)blockIdx.x * RPB;

    float part[E][RPB];
#pragma unroll
    for (int e = 0; e < E; ++e)
#pragma unroll
        for (int r = 0; r < RPB; ++r) part[e][r] = 0.f;

    for (int k = 0; k < chunks; ++k) {
        const int d4 = k * TPB + t;
        float4 hp[E];
#pragma unroll
        for (int e = 0; e < E; ++e) hp[e] = pre4[(size_t)e * D4 + d4];
#pragma unroll
        for (int r = 0; r < RPB; ++r) {
            float4 xv = x4[(row0 + r) * D4 + d4];
#pragma unroll
            for (int e = 0; e < E; ++e) {
                part[e][r] += xv.x * hp[e].x + xv.y * hp[e].y +
                              xv.z * hp[e].z + xv.w * hp[e].w;
            }
        }
    }

    // wave-level butterfly reduce, then cross-wave via LDS
#pragma unroll
    for (int e = 0; e < E; ++e) {
#pragma unroll
        for (int r = 0; r < RPB; ++r) {
            float v = part[e][r];
#pragma unroll
            for (int off = 32; off > 0; off >>= 1) v += __shfl_xor(v, off, 64);
            part[e][r] = v;
        }
    }
    if ((t & 63) == 0) {
#pragma unroll
        for (int e = 0; e < E; ++e)
#pragma unroll
            for (int r = 0; r < RPB; ++r) wred[wave][e][r] = part[e][r];
    }
    __syncthreads();

    float xp[RPB][E];
#pragma unroll
    for (int r = 0; r < RPB; ++r)
#pragma unroll
        for (int e = 0; e < E; ++e) {
            float v = 0.f;
#pragma unroll
            for (int w = 0; w < NWAVES; ++w) v += wred[w][e][r];
            xp[r][e] = v;
        }

    for (int k = 0; k < chunks; ++k) {
        const int d4 = k * TPB + t;
        float4 hq[E];
#pragma unroll
        for (int e = 0; e < E; ++e) hq[e] = post4[(size_t)e * D4 + d4];
#pragma unroll
        for (int r = 0; r < RPB; ++r) {
            float4 o;
            o.x = xp[r][0] * hq[0].x + xp[r][1] * hq[1].x + xp[r][2] * hq[2].x + xp[r][3] * hq[3].x;
            o.y = xp[r][0] * hq[0].y + xp[r][1] * hq[1].y + xp[r][2] * hq[2].y + xp[r][3] * hq[3].y;
            o.z = xp[r][0] * hq[0].z + xp[r][1] * hq[1].z + xp[r][2] * hq[2].z + xp[r][3] * hq[3].z;
            o.w = xp[r][0] * hq[0].w + xp[r][1] * hq[1].w + xp[r][2] * hq[2].w + xp[r][3] * hq[3].w;
            out4[(row0 + r) * D4 + d4] = o;
        }
    }
}

extern "C" void kernel_launch(void* const* d_in, const int* in_sizes, int n_in,
                              void* d_out, int out_size, void* d_ws, size_t ws_size,
                              hipStream_t stream) {
    const float* x     = (const float*)d_in[0];
    const float* Hres  = (const float*)d_in[1];
    const float* Hpre  = (const float*)d_in[2];
    const float* Hpost = (const float*)d_in[3];
    float* out = (float*)d_out;

    const int D = in_sizes[2] / E;                  // 4096
    const long rows = (long)in_sizes[0] / D;        // B*S = 16384

    float* ws_pre   = (float*)d_ws;                 // E*D floats
    float* ws_post2 = ws_pre + (size_t)E * D;       // E*D floats

    prep_kernel<<<1, TPB, 0, stream>>>(Hres, Hpre, Hpost, ws_pre, ws_post2, D);

    const int D4 = D / 4;
    const int chunks = D4 / TPB;                    // 4
    const int grid = (int)(rows / RPB);             // 2048
    mhc_main<<<grid, TPB, 0, stream>>>((const float4*)x, (const float4*)ws_pre,
                                       (const float4*)ws_post2, (float4*)out,
                                       D4, chunks);
}

// Round 2
// 131.214 us; speedup vs baseline: 1.5989x; 1.5989x over previous
//
#include <hip/hip_runtime.h>
#include <math.h>

#define E 4
#define TPB 256
#define RPB 8
#define NWAVES (TPB / 64)
#define SINKHORN_ITERS 20
#define SINKHORN_EPS 1e-6f

typedef float f4 __attribute__((ext_vector_type(4)));

// ---------------------------------------------------------------------------
// Kernel 0: prep (1 block, fully parallel — no serial sinkhorn, ~2 barriers).
//  wave 0 lanes 0-15: sinkhorn(H_res_logits) via width-4/16 shfl butterflies
//  each wave: softmax stats (max,sumexp) for 2 of the 8 (mat,row) pairs
//  all 256 threads: write ws_pre = softmax(H_pre),
//                   ws_post2 = H_res @ softmax(H_post)   (E x D each)
// ---------------------------------------------------------------------------
__global__ __launch_bounds__(TPB) void prep_kernel(
    const float* __restrict__ Hres_l,
    const float* __restrict__ Hpre_l,
    const float* __restrict__ Hpost_l,
    float* __restrict__ ws_pre,
    float* __restrict__ ws_post2,
    int D)
{
    __shared__ float sHres[E * E];
    __shared__ float smx[2 * E], ssm[2 * E];
    const int t = threadIdx.x;
    const int wave = t >> 6;
    const int lane = t & 63;
    const int D4 = D >> 2;

    if (wave == 0) {
        // --- sinkhorn on lanes 0..15 (lane = r*4 + c) ---
        float a = (lane < E * E) ? Hres_l[lane] : -1e30f;
        float m = a;
#pragma unroll
        for (int off = 1; off < 16; off <<= 1)
            m = fmaxf(m, __shfl_xor(m, off, 16));
        a = expf(a - m);
        for (int it = 0; it < SINKHORN_ITERS; ++it) {
            float rs = a;                       // row sum: lanes sharing r (width-4 group)
            rs += __shfl_xor(rs, 1, 4);
            rs += __shfl_xor(rs, 2, 4);
            a /= (rs + SINKHORN_EPS);
            float cs = a;                       // col sum: lanes sharing c (xor 4,8 in width 16)
            cs += __shfl_xor(cs, 4, 16);
            cs += __shfl_xor(cs, 8, 16);
            a /= (cs + SINKHORN_EPS);
        }
        if (lane < E * E) sHres[lane] = a;
    }

    // --- softmax stats: wave handles pairs p = 2*wave, 2*wave+1 ---
    for (int pi = 0; pi < 2; ++pi) {
        const int p = wave * 2 + pi;
        const int mat = p >> 2, e = p & 3;
        const f4* rowp = (const f4*)((mat ? Hpost_l : Hpre_l) + (size_t)e * D);
        float m = -1e30f;
        for (int i = lane; i < D4; i += 64) {
            f4 v = rowp[i];
            m = fmaxf(fmaxf(fmaxf(m, v.x), v.y), fmaxf(v.z, v.w));
        }
#pragma unroll
        for (int off = 1; off < 64; off <<= 1)
            m = fmaxf(m, __shfl_xor(m, off, 64));
        float s = 0.f;
        for (int i = lane; i < D4; i += 64) {
            f4 v = rowp[i];
            s += expf(v.x - m) + expf(v.y - m) + expf(v.z - m) + expf(v.w - m);
        }
#pragma unroll
        for (int off = 1; off < 64; off <<= 1)
            s += __shfl_xor(s, off, 64);
        if (lane == 0) { smx[p] = m; ssm[p] = s; }
    }
    __syncthreads();

    float hres[E * E];
#pragma unroll
    for (int i = 0; i < E * E; ++i) hres[i] = sHres[i];
    float mpre[E], spre[E], mpost[E], spost[E];
#pragma unroll
    for (int e = 0; e < E; ++e) {
        mpre[e] = smx[e];      spre[e] = 1.f / ssm[e];
        mpost[e] = smx[E + e]; spost[e] = 1.f / ssm[E + e];
    }

    const f4* pre_l4  = (const f4*)Hpre_l;
    const f4* post_l4 = (const f4*)Hpost_l;
    f4* wpre4  = (f4*)ws_pre;
    f4* wpost4 = (f4*)ws_post2;
    for (int i = t; i < D4; i += TPB) {
        f4 postv[E];
#pragma unroll
        for (int e = 0; e < E; ++e) {
            f4 v = pre_l4[(size_t)e * D4 + i];
            f4 o;
            o.x = expf(v.x - mpre[e]) * spre[e];
            o.y = expf(v.y - mpre[e]) * spre[e];
            o.z = expf(v.z - mpre[e]) * spre[e];
            o.w = expf(v.w - mpre[e]) * spre[e];
            wpre4[(size_t)e * D4 + i] = o;
            f4 w = post_l4[(size_t)e * D4 + i];
            postv[e].x = expf(w.x - mpost[e]) * spost[e];
            postv[e].y = expf(w.y - mpost[e]) * spost[e];
            postv[e].z = expf(w.z - mpost[e]) * spost[e];
            postv[e].w = expf(w.w - mpost[e]) * spost[e];
        }
#pragma unroll
        for (int ep = 0; ep < E; ++ep) {
            f4 o = hres[ep * E + 0] * postv[0] + hres[ep * E + 1] * postv[1] +
                   hres[ep * E + 2] * postv[2] + hres[ep * E + 3] * postv[3];
            wpost4[(size_t)ep * D4 + i] = o;
        }
    }
}

// ---------------------------------------------------------------------------
// Kernel 1: x_pre[row][e] = dot(x[row], ws_pre[e]). Pure read stream of x
// (nontemporal — x is never re-read). 8 rows per 256-thread block.
// ---------------------------------------------------------------------------
__global__ __launch_bounds__(TPB) void xpre_kernel(
    const f4* __restrict__ x4,
    const f4* __restrict__ pre4,
    float* __restrict__ xpre,
    int D4, int chunks)
{
    __shared__ float wred[NWAVES][RPB][E];
    const int t = threadIdx.x;
    const int wave = t >> 6;
    const long row0 = (long)blockIdx.x * RPB;

    float part[RPB][E];
#pragma unroll
    for (int r = 0; r < RPB; ++r)
#pragma unroll
        for (int e = 0; e < E; ++e) part[r][e] = 0.f;

    for (int k = 0; k < chunks; ++k) {
        const int d4 = k * TPB + t;
        f4 hp[E];
#pragma unroll
        for (int e = 0; e < E; ++e) hp[e] = pre4[(size_t)e * D4 + d4];
#pragma unroll
        for (int r = 0; r < RPB; ++r) {
            f4 xv = __builtin_nontemporal_load(&x4[(row0 + r) * D4 + d4]);
#pragma unroll
            for (int e = 0; e < E; ++e)
                part[r][e] += xv.x * hp[e].x + xv.y * hp[e].y +
                              xv.z * hp[e].z + xv.w * hp[e].w;
        }
    }

#pragma unroll
    for (int r = 0; r < RPB; ++r)
#pragma unroll
        for (int e = 0; e < E; ++e) {
            float v = part[r][e];
#pragma unroll
            for (int off = 1; off < 64; off <<= 1) v += __shfl_xor(v, off, 64);
            if ((t & 63) == 0) wred[wave][r][e] = v;
        }
    __syncthreads();

    if (t < RPB * E) {
        const int r = t >> 2, e = t & 3;
        float v = 0.f;
#pragma unroll
        for (int w = 0; w < NWAVES; ++w) v += wred[w][r][e];
        xpre[(row0 + r) * E + e] = v;
    }
}

// ---------------------------------------------------------------------------
// Kernel 2: out[row][d] = sum_e x_pre[row][e] * ws_post2[e][d].
// Pure write stream (nontemporal stores — out never re-read).
// ---------------------------------------------------------------------------
__global__ __launch_bounds__(TPB) void out_kernel(
    const float* __restrict__ xpre,
    const f4* __restrict__ post4,
    f4* __restrict__ out4,
    int D4, int chunks)
{
    __shared__ float sxp[RPB * E];
    const int t = threadIdx.x;
    const long row0 = (long)blockIdx.x * RPB;

    if (t < RPB * E) sxp[t] = xpre[row0 * E + t];
    __syncthreads();

    float xp[RPB][E];
#pragma unroll
    for (int r = 0; r < RPB; ++r)
#pragma unroll
        for (int e = 0; e < E; ++e) xp[r][e] = sxp[r * E + e];

    for (int k = 0; k < chunks; ++k) {
        const int d4 = k * TPB + t;
        f4 hq[E];
#pragma unroll
        for (int e = 0; e < E; ++e) hq[e] = post4[(size_t)e * D4 + d4];
#pragma unroll
        for (int r = 0; r < RPB; ++r) {
            f4 o = xp[r][0] * hq[0] + xp[r][1] * hq[1] +
                   xp[r][2] * hq[2] + xp[r][3] * hq[3];
            __builtin_nontemporal_store(o, &out4[(row0 + r) * D4 + d4]);
        }
    }
}

extern "C" void kernel_launch(void* const* d_in, const int* in_sizes, int n_in,
                              void* d_out, int out_size, void* d_ws, size_t ws_size,
                              hipStream_t stream) {
    const float* x     = (const float*)d_in[0];
    const float* Hres  = (const float*)d_in[1];
    const float* Hpre  = (const float*)d_in[2];
    const float* Hpost = (const float*)d_in[3];
    float* out = (float*)d_out;

    const int D = in_sizes[2] / E;                  // 4096
    const long rows = (long)in_sizes[0] / D;        // B*S = 16384

    float* ws_pre   = (float*)d_ws;                 // E*D floats
    float* ws_post2 = ws_pre + (size_t)E * D;       // E*D floats
    float* ws_xpre  = ws_post2 + (size_t)E * D;     // rows*E floats

    prep_kernel<<<1, TPB, 0, stream>>>(Hres, Hpre, Hpost, ws_pre, ws_post2, D);

    const int D4 = D / 4;
    const int chunks = D4 / TPB;                    // 4
    const int grid = (int)(rows / RPB);             // 2048

    xpre_kernel<<<grid, TPB, 0, stream>>>((const f4*)x, (const f4*)ws_pre,
                                          ws_xpre, D4, chunks);
    out_kernel<<<grid, TPB, 0, stream>>>(ws_xpre, (const f4*)ws_post2,
                                         (f4*)out, D4, chunks);
}